// Round 3
// baseline (1528.640 us; speedup 1.0000x reference)
//
#include <hip/hip_runtime.h>

// RGCN block-diagonal layer, f32.
// out = relu( (scatter_sum(msg) * norm) + bias + h @ loop_weight )
// msg[e, b*16+o] = sum_i h[src[e], b*16+i] * W[type[e], b*256 + i*16 + o]
//
// v3 pipeline (kills global atomics AND weight re-fetch):
//   A: init_kernel : out[n][:] = bias + h[n] @ loop_weight      (LDS-staged LW)
//   Z: zero cnt
//   H: histogram over bins = (dst>>6)*16 + type                 (25K bins)
//   S: single-block scan -> bin_ptr, cursor
//   C: scatter srec[p] = (src<<6)|(dst&63), type-implicit       (4 B/edge)
//   B: edge_lds : block = one 64-dst range, 32KB LDS accum;
//      8 waves x 2 types each, W in regs; LDS atomics; flush =
//      out[d] = relu(out[d] + acc*norm[d])   (non-atomic, fused relu)

#define RANGE_BITS 6
#define RANGE (1 << RANGE_BITS)

__global__ __launch_bounds__(256) void rgcn_init_kernel(
    const float* __restrict__ h, const float* __restrict__ loop_w,
    const float* __restrict__ bias, float* __restrict__ out, int N) {
  __shared__ float lw[128 * 128];  // 64 KB
  for (int idx = threadIdx.x; idx < 128 * 128 / 4; idx += 256) {
    ((float4*)lw)[idx] = ((const float4*)loop_w)[idx];
  }
  __syncthreads();

  const int lane = threadIdx.x & 63;
  const int wid = threadIdx.x >> 6;
  const int group0 = blockIdx.x * 4 + wid;
  const int ngroups = gridDim.x * 4;
  const int totgroups = (N + 3) >> 2;
  const float b0 = bias[lane];
  const float b1 = bias[64 + lane];

  for (int g = group0; g < totgroups; g += ngroups) {
    const int n0 = g * 4;
    const int nn = (N - n0 < 4) ? (N - n0) : 4;
    if (nn == 4) {
      const float* __restrict__ r0 = h + (size_t)n0 * 128;
      const float* __restrict__ r1 = r0 + 128;
      const float* __restrict__ r2 = r1 + 128;
      const float* __restrict__ r3 = r2 + 128;
      float a00 = b0, a01 = b1, a10 = b0, a11 = b1;
      float a20 = b0, a21 = b1, a30 = b0, a31 = b1;
#pragma unroll 4
      for (int k = 0; k < 128; ++k) {
        const float w0 = lw[k * 128 + lane];
        const float w1 = lw[k * 128 + 64 + lane];
        a00 = fmaf(r0[k], w0, a00); a01 = fmaf(r0[k], w1, a01);
        a10 = fmaf(r1[k], w0, a10); a11 = fmaf(r1[k], w1, a11);
        a20 = fmaf(r2[k], w0, a20); a21 = fmaf(r2[k], w1, a21);
        a30 = fmaf(r3[k], w0, a30); a31 = fmaf(r3[k], w1, a31);
      }
      float* __restrict__ o0 = out + (size_t)n0 * 128;
      o0[lane] = a00;        o0[64 + lane] = a01;
      o0[128 + lane] = a10;  o0[192 + lane] = a11;
      o0[256 + lane] = a20;  o0[320 + lane] = a21;
      o0[384 + lane] = a30;  o0[448 + lane] = a31;
    } else {
      for (int r = 0; r < nn; ++r) {
        const int n = n0 + r;
        const float* __restrict__ hr = h + (size_t)n * 128;
        float a0 = b0, a1 = b1;
#pragma unroll 4
        for (int k = 0; k < 128; ++k) {
          const float a = hr[k];
          a0 = fmaf(a, lw[k * 128 + lane], a0);
          a1 = fmaf(a, lw[k * 128 + 64 + lane], a1);
        }
        out[(size_t)n * 128 + lane] = a0;
        out[(size_t)n * 128 + 64 + lane] = a1;
      }
    }
  }
}

__global__ __launch_bounds__(256) void rgcn_zero_kernel(int* __restrict__ p,
                                                        int n) {
  for (int i = blockIdx.x * 256 + threadIdx.x; i < n; i += gridDim.x * 256)
    p[i] = 0;
}

__global__ __launch_bounds__(256) void rgcn_hist_kernel(
    const int* __restrict__ edst, const int* __restrict__ etype,
    int* __restrict__ cnt, int E) {
  for (int e = blockIdx.x * 256 + threadIdx.x; e < E; e += gridDim.x * 256) {
    const int bin = ((edst[e] >> RANGE_BITS) << 4) + etype[e];
    atomicAdd(&cnt[bin], 1);
  }
}

__global__ __launch_bounds__(1024) void rgcn_scan_kernel(
    const int* __restrict__ cnt, int* __restrict__ bin_ptr,
    int* __restrict__ cursor, int bins) {
  __shared__ int part[1024];
  const int t = threadIdx.x;
  const int chunk = (bins + 1023) >> 10;
  const int lo = t * chunk;
  const int hi = min(bins, lo + chunk);
  int s = 0;
  for (int i = lo; i < hi; ++i) s += cnt[i];
  part[t] = s;
  __syncthreads();
#pragma unroll
  for (int off = 1; off < 1024; off <<= 1) {
    const int add = (t >= off) ? part[t - off] : 0;
    __syncthreads();
    part[t] += add;
    __syncthreads();
  }
  int run = (t == 0) ? 0 : part[t - 1];
  for (int i = lo; i < hi; ++i) {
    const int c = cnt[i];
    bin_ptr[i] = run;
    cursor[i] = run;
    run += c;
  }
  if (t == 1023) bin_ptr[bins] = part[1023];
}

__global__ __launch_bounds__(256) void rgcn_scatter_kernel(
    const int* __restrict__ esrc, const int* __restrict__ edst,
    const int* __restrict__ etype, int* __restrict__ cursor,
    int* __restrict__ srec, int E) {
  for (int e = blockIdx.x * 256 + threadIdx.x; e < E; e += gridDim.x * 256) {
    const int d = edst[e];
    const int bin = ((d >> RANGE_BITS) << 4) + etype[e];
    const int p = atomicAdd(&cursor[bin], 1);
    srec[p] = (esrc[e] << RANGE_BITS) | (d & (RANGE - 1));
  }
}

// One block per 64-dst range. 8 waves; wave w owns types {2w, 2w+1} with the
// full 8 KB weight block in registers. Edges pre-grouped by (range, type).
// Accumulate via LDS atomics; flush non-atomically with norm + fused relu.
__global__ __launch_bounds__(512) void rgcn_edge_lds_kernel(
    const float* __restrict__ h, const float* __restrict__ norm,
    const int* __restrict__ srec, const int* __restrict__ bin_ptr,
    const float* __restrict__ weight, float* __restrict__ out, int N) {
  __shared__ float acc[RANGE * 128];  // 32 KB
  for (int idx = threadIdx.x; idx < RANGE * 128 / 4; idx += 512)
    ((float4*)acc)[idx] = make_float4(0.f, 0.f, 0.f, 0.f);
  __syncthreads();

  const int lane = threadIdx.x & 63;
  const int w = threadIdx.x >> 6;  // wave 0..7
  const int b = lane >> 4;         // block 0..3 (lo half); hi uses b+4
  const int o = lane & 15;
  const int r = blockIdx.x;

  for (int tt = 0; tt < 2; ++tt) {
    const int t = w * 2 + tt;
    const int e0 = bin_ptr[r * 16 + t];
    const int e1 = bin_ptr[r * 16 + t + 1];
    if (e0 == e1) continue;

    const float* __restrict__ wb = weight + t * 2048 + b * 256 + o;
    float wlo[16], whi[16];
#pragma unroll
    for (int i = 0; i < 16; ++i) {
      wlo[i] = wb[i * 16];
      whi[i] = wb[1024 + i * 16];
    }

#pragma unroll 2
    for (int e = e0; e < e1; ++e) {
      const int rec = srec[e];
      const int src = rec >> RANGE_BITS;
      const int dl = rec & (RANGE - 1);

      const float4* __restrict__ hp =
          (const float4*)(h + (size_t)src * 128) + (b << 2);
      const float4 x0 = hp[0], x1 = hp[1], x2 = hp[2], x3 = hp[3];
      const float4 y0 = hp[16], y1 = hp[17], y2 = hp[18], y3 = hp[19];

      float a0 = x0.x * wlo[0], a1 = x0.y * wlo[1];
      a0 = fmaf(x0.z, wlo[2], a0);  a1 = fmaf(x0.w, wlo[3], a1);
      a0 = fmaf(x1.x, wlo[4], a0);  a1 = fmaf(x1.y, wlo[5], a1);
      a0 = fmaf(x1.z, wlo[6], a0);  a1 = fmaf(x1.w, wlo[7], a1);
      a0 = fmaf(x2.x, wlo[8], a0);  a1 = fmaf(x2.y, wlo[9], a1);
      a0 = fmaf(x2.z, wlo[10], a0); a1 = fmaf(x2.w, wlo[11], a1);
      a0 = fmaf(x3.x, wlo[12], a0); a1 = fmaf(x3.y, wlo[13], a1);
      a0 = fmaf(x3.z, wlo[14], a0); a1 = fmaf(x3.w, wlo[15], a1);

      float c0 = y0.x * whi[0], c1 = y0.y * whi[1];
      c0 = fmaf(y0.z, whi[2], c0);  c1 = fmaf(y0.w, whi[3], c1);
      c0 = fmaf(y1.x, whi[4], c0);  c1 = fmaf(y1.y, whi[5], c1);
      c0 = fmaf(y1.z, whi[6], c0);  c1 = fmaf(y1.w, whi[7], c1);
      c0 = fmaf(y2.x, whi[8], c0);  c1 = fmaf(y2.y, whi[9], c1);
      c0 = fmaf(y2.z, whi[10], c0); c1 = fmaf(y2.w, whi[11], c1);
      c0 = fmaf(y3.x, whi[12], c0); c1 = fmaf(y3.y, whi[13], c1);
      c0 = fmaf(y3.z, whi[14], c0); c1 = fmaf(y3.w, whi[15], c1);

      atomicAdd(&acc[dl * 128 + lane], a0 + a1);
      atomicAdd(&acc[dl * 128 + 64 + lane], c0 + c1);
    }
  }
  __syncthreads();

  // flush: out[d] = relu(out[d] + acc*norm[d]), 32 float4 per dst row
  for (int idx = threadIdx.x; idx < RANGE * 32; idx += 512) {
    const int dl = idx >> 5;
    const int c4 = idx & 31;
    const int d = (r << RANGE_BITS) + dl;
    if (d < N) {
      const float nm = norm[d];
      const float4 a = ((const float4*)acc)[idx];
      float4 ov = ((float4*)out)[d * 32 + c4];
      ov.x = fmaxf(fmaf(a.x, nm, ov.x), 0.f);
      ov.y = fmaxf(fmaf(a.y, nm, ov.y), 0.f);
      ov.z = fmaxf(fmaf(a.z, nm, ov.z), 0.f);
      ov.w = fmaxf(fmaf(a.w, nm, ov.w), 0.f);
      ((float4*)out)[d * 32 + c4] = ov;
    }
  }
}

// Fallback (ws too small / unexpected shape): unsorted atomic edge kernel.
__global__ __launch_bounds__(256) void rgcn_edge_kernel(
    const float* __restrict__ h, const float* __restrict__ norm,
    const int* __restrict__ esrc, const int* __restrict__ edst,
    const int* __restrict__ etype, const float* __restrict__ weight,
    float* __restrict__ out, int E) {
  const int lane = threadIdx.x & 63;
  const int wid = threadIdx.x >> 6;
  const int wave0 = blockIdx.x * 4 + wid;
  const int nwaves = gridDim.x * 4;
  const int b = lane >> 4;
  const int o = lane & 15;

  for (int e = wave0; e < E; e += nwaves) {
    const int src = esrc[e];
    const int dst = edst[e];
    const int et = etype[e];
    const float s_lo = h[src * 128 + lane];
    const float s_hi = h[src * 128 + 64 + lane];
    const float nrm = norm[dst];
    const float* __restrict__ Wb = weight + et * 2048 + b * 256 + o;
    float m0 = 0.f, m1 = 0.f;
#pragma unroll
    for (int i = 0; i < 16; ++i) {
      const float a_lo = __shfl(s_lo, (lane & 48) + i, 64);
      const float a_hi = __shfl(s_hi, (lane & 48) + i, 64);
      m0 = fmaf(a_lo, Wb[i * 16], m0);
      m1 = fmaf(a_hi, Wb[1024 + i * 16], m1);
    }
    atomicAdd(&out[dst * 128 + lane], m0 * nrm);
    atomicAdd(&out[dst * 128 + 64 + lane], m1 * nrm);
  }
}

__global__ __launch_bounds__(256) void rgcn_relu_kernel(float* __restrict__ out,
                                                        int total4) {
  int i = blockIdx.x * 256 + threadIdx.x;
  const int stride = gridDim.x * 256;
  for (; i < total4; i += stride) {
    float4 v = ((float4*)out)[i];
    v.x = fmaxf(v.x, 0.f);
    v.y = fmaxf(v.y, 0.f);
    v.z = fmaxf(v.z, 0.f);
    v.w = fmaxf(v.w, 0.f);
    ((float4*)out)[i] = v;
  }
}

extern "C" void kernel_launch(void* const* d_in, const int* in_sizes, int n_in,
                              void* d_out, int out_size, void* d_ws, size_t ws_size,
                              hipStream_t stream) {
  const float* h      = (const float*)d_in[0];
  const float* norm   = (const float*)d_in[1];
  const int*   esrc   = (const int*)d_in[2];
  const int*   edst   = (const int*)d_in[3];
  const int*   etype  = (const int*)d_in[4];
  const float* weight = (const float*)d_in[5];
  const float* bias   = (const float*)d_in[6];
  const float* loop_w = (const float*)d_in[7];
  float* out = (float*)d_out;

  const int N = in_sizes[0] / 128;
  const int E = in_sizes[2];
  const int nrels = in_sizes[5] / 2048;

  rgcn_init_kernel<<<2048, 256, 0, stream>>>(h, loop_w, bias, out, N);

  const int nRanges = (N + RANGE - 1) >> RANGE_BITS;
  const int bins = nRanges * 16;
  // ws: cnt[bins] | bin_ptr[bins+1] | cursor[bins] | srec[E]
  const size_t need = ((size_t)(3 * bins + 8) + (size_t)E) * 4;

  if (nrels == 16 && N < (1 << 25) && ws_size >= need) {
    int* cnt     = (int*)d_ws;
    int* bin_ptr = cnt + bins;
    int* cursor  = bin_ptr + bins + 4;  // padded
    int* srec    = cursor + bins;

    rgcn_zero_kernel<<<64, 256, 0, stream>>>(cnt, bins);
    rgcn_hist_kernel<<<1024, 256, 0, stream>>>(edst, etype, cnt, E);
    rgcn_scan_kernel<<<1, 1024, 0, stream>>>(cnt, bin_ptr, cursor, bins);
    rgcn_scatter_kernel<<<2048, 256, 0, stream>>>(esrc, edst, etype, cursor,
                                                  srec, E);
    rgcn_edge_lds_kernel<<<nRanges, 512, 0, stream>>>(h, norm, srec, bin_ptr,
                                                      weight, out, N);
  } else {
    rgcn_edge_kernel<<<4096, 256, 0, stream>>>(h, norm, esrc, edst, etype,
                                               weight, out, E);
    rgcn_relu_kernel<<<2048, 256, 0, stream>>>(out, (N * 128) / 4);
  }
}